// Round 3
// baseline (1186.963 us; speedup 1.0000x reference)
//
#include <hip/hip_runtime.h>
#include <math.h>

#define N_ATOMS 50000
#define N_EDGES 1600000
#define NRBF 20
#define TILE_E 32
#define N_TILES (N_EDGES / TILE_E)   // 50000 exact

typedef __attribute__((ext_vector_type(8))) short bf16x8;
typedef __attribute__((ext_vector_type(4))) short s16x4;
typedef __attribute__((ext_vector_type(4))) float f32x4;

__device__ __forceinline__ float sp(float v) {    // softplus (stable), NO -ln2 shift
    const float a = fabsf(v);
    const float e = exp2f(a * -1.4426950408889634f);
    const float l = log2f(1.0f + e);
    return fmaxf(v, 0.0f) + l * 0.6931471805599453f;
}
__device__ __forceinline__ float ssp(float v) {   // shifted softplus
    const float a = fabsf(v);
    const float e = exp2f(a * -1.4426950408889634f);
    const float l = log2f(1.0f + e);
    return fmaxf(v, 0.0f) + fmaf(l, 0.6931471805599453f, -0.6931471805599453f);
}
__device__ __forceinline__ unsigned short f2bf(float f) {   // fp32 -> bf16 bits, RNE
    unsigned int u = __float_as_uint(f);
    u += 0x7fff + ((u >> 16) & 1);
    return (unsigned short)(u >> 16);
}
__device__ __forceinline__ float bf2f(unsigned short b) {
    return __uint_as_float(((unsigned int)b) << 16);
}
// LDS-only barrier: drains lgkmcnt but NOT vmcnt, so register prefetches of
// global data survive across phases (all inter-wave traffic goes through LDS).
__device__ __forceinline__ void lds_barrier() {
    __asm__ __volatile__("s_waitcnt lgkmcnt(0)\ns_barrier" ::: "memory");
}

// ---------------------------------------------------------------------------
// Row-GEMM (R1-verified body): A tile staged once per block through LDS
// (bf16 hi/lo planes, scalar f2bf). zbuf!=nullptr: grid-stride-zero that
// buffer first (folds the y-memset into dispatch 1).
template<bool SSP_ACT, bool BIAS>
__global__ __launch_bounds__(512) void rowgemm2(
    const float* __restrict__ A, const float* __restrict__ W,
    const float* __restrict__ bias, float* __restrict__ C, int nrows,
    float* __restrict__ zbuf)
{
    __shared__ short sAh[32][136];   // row stride 272B -> bank-balanced b128
    __shared__ short sAl[32][136];

    if (zbuf) {
        const int n4 = N_ATOMS * 128 / 4;
        const float4 z = {0.0f, 0.0f, 0.0f, 0.0f};
        for (int i = blockIdx.x * blockDim.x + threadIdx.x; i < n4;
             i += gridDim.x * blockDim.x)
            ((float4*)zbuf)[i] = z;
    }

    const int tid  = threadIdx.x;
    const int wave = tid >> 6, lane = tid & 63;
    const int l15  = lane & 15, quad = lane >> 4;
    const int rhalf = wave >> 2, cpair = wave & 3;
    const int r0 = rhalf * 16;
    const int ntiles = (nrows + 31) >> 5;
    const int stride = gridDim.x;

    const int sr0 = tid >> 5;            // rows 0..15
    const int sr1 = sr0 + 16;            // rows 16..31
    const int sc0 = (tid & 31) * 4;      // col group

    // ---- W fragments (hi/lo) + bias, once per block ----
    bf16x8 wh[2][4], wl[2][4];
    float br[2];
    #pragma unroll
    for (int ct = 0; ct < 2; ++ct) {
        const int c = cpair * 32 + ct * 16 + l15;
        br[ct] = BIAS ? bias[c] : 0.0f;
        #pragma unroll
        for (int kk = 0; kk < 4; ++kk) {
            #pragma unroll
            for (int j = 0; j < 8; ++j) {
                const int k = kk * 32 + quad * 8 + j;
                const float v = W[k * 128 + c];
                const unsigned short hb = f2bf(v);
                wh[ct][kk][j] = (short)hb;
                wl[ct][kk][j] = (short)f2bf(v - bf2f(hb));
            }
        }
    }

    int t = blockIdx.x;
    if (t >= ntiles) return;

    float4 v0, v1;
    {
        const int ra = t * 32 + sr0, rb = t * 32 + sr1;
        v0 = *(const float4*)(A + (size_t)((ra < nrows) ? ra : nrows - 1) * 128 + sc0);
        v1 = *(const float4*)(A + (size_t)((rb < nrows) ? rb : nrows - 1) * 128 + sc0);
    }

    while (true) {
        // ---- stage tile t into LDS (scalar f2bf hi/lo, R1-verified) ----
        {
            const float fa[4] = {v0.x, v0.y, v0.z, v0.w};
            const float fb[4] = {v1.x, v1.y, v1.z, v1.w};
            s16x4 ha, la, hbv, lb;
            #pragma unroll
            for (int j = 0; j < 4; ++j) {
                const unsigned short h0 = f2bf(fa[j]);
                ha[j] = (short)h0; la[j] = (short)f2bf(fa[j] - bf2f(h0));
                const unsigned short h1 = f2bf(fb[j]);
                hbv[j] = (short)h1; lb[j] = (short)f2bf(fb[j] - bf2f(h1));
            }
            *(s16x4*)(&sAh[sr0][sc0]) = ha;  *(s16x4*)(&sAl[sr0][sc0]) = la;
            *(s16x4*)(&sAh[sr1][sc0]) = hbv; *(s16x4*)(&sAl[sr1][sc0]) = lb;
        }
        __syncthreads();

        const int tn = t + stride;
        const bool more = (tn < ntiles);
        float4 n0, n1;
        if (more) {   // prefetch next tile while MFMAs run
            const int ra = tn * 32 + sr0, rb = tn * 32 + sr1;
            n0 = *(const float4*)(A + (size_t)((ra < nrows) ? ra : nrows - 1) * 128 + sc0);
            n1 = *(const float4*)(A + (size_t)((rb < nrows) ? rb : nrows - 1) * 128 + sc0);
        }

        bf16x8 ah[4], al[4];
        #pragma unroll
        for (int kk = 0; kk < 4; ++kk) {
            ah[kk] = *(const bf16x8*)(&sAh[r0 + l15][kk * 32 + quad * 8]);
            al[kk] = *(const bf16x8*)(&sAl[r0 + l15][kk * 32 + quad * 8]);
        }
        #pragma unroll
        for (int ct = 0; ct < 2; ++ct) {
            f32x4 acc = {0.0f, 0.0f, 0.0f, 0.0f};
            #pragma unroll
            for (int kk = 0; kk < 4; ++kk) {
                acc = __builtin_amdgcn_mfma_f32_16x16x32_bf16(ah[kk], wh[ct][kk], acc, 0, 0, 0);
                acc = __builtin_amdgcn_mfma_f32_16x16x32_bf16(al[kk], wh[ct][kk], acc, 0, 0, 0);
                acc = __builtin_amdgcn_mfma_f32_16x16x32_bf16(ah[kk], wl[ct][kk], acc, 0, 0, 0);
            }
            const int c = cpair * 32 + ct * 16 + l15;
            #pragma unroll
            for (int r = 0; r < 4; ++r) {
                const int row = t * 32 + r0 + quad * 4 + r;
                if (row < nrows) {
                    float v = acc[r] + br[ct];
                    if (SSP_ACT) v = ssp(v);
                    C[(size_t)row * 128 + c] = v;
                }
            }
        }
        if (!more) break;
        __syncthreads();
        v0 = n0; v1 = n1; t = tn;
    }
}

// ---------------------------------------------------------------------------
// Fused edge kernel, v3 = R2 structure with R1-verified numerics (scalar
// f2bf, stable sp). Lean pipeline targeting VGPR<=64 (8 waves/SIMD -> 4
// blocks/CU): only f_ij(t+1) and idx_j-offsets(t+1) carried cross-iter; h
// gathered at top of its own iteration (consumer is past layer1+B1+8 MFMA).
__global__ __launch_bounds__(512, 8) void edge_mfma(
    const float* __restrict__ f_ij, const float* __restrict__ rcut,
    const int* __restrict__ idx_i, const int* __restrict__ idx_j,
    const float* __restrict__ h,
    const float* __restrict__ W1, const float* __restrict__ b1,
    const float* __restrict__ W2, const float* __restrict__ b2,
    float* __restrict__ y)
{
    __shared__ unsigned short sTH[32][136];   // t tile, bf16-hi
    __shared__ float sXT[128][36];            // xij^T; stride 36 -> aligned b128

    const int tid  = threadIdx.x;
    const int wave = tid >> 6, lane = tid & 63;
    const int l15  = lane & 15, quad = lane >> 4;
    const int rhalf = wave >> 2, cpair = wave & 3;
    const int r0  = rhalf * 16;
    const int c0  = cpair * 32 + l15;
    const int rr  = r0 + quad * 4;
    const int col = tid & 127, qtr = tid >> 7;

    // ---- weight fragments ----
    bf16x8 w1h[2];
    bf16x8 w2h[2][4];
    float b1r[2], b2r[2];
    #pragma unroll
    for (int ct = 0; ct < 2; ++ct) {
        const int c = c0 + ct * 16;
        b1r[ct] = b1[c];
        #pragma unroll
        for (int j = 0; j < 8; ++j) {
            const int k = quad * 8 + j;
            w1h[ct][j] = (short)f2bf((k < NRBF) ? W1[k * 128 + c] : 0.0f);
        }
        float csum = 0.0f;
        #pragma unroll
        for (int kk = 0; kk < 4; ++kk) {
            #pragma unroll
            for (int j = 0; j < 8; ++j) {
                const float wv = W2[(kk * 32 + quad * 8 + j) * 128 + c];
                const unsigned short hb = f2bf(wv);
                w2h[ct][kk][j] = (short)hb;
                csum += bf2f(hb);
            }
        }
        csum += __shfl_xor(csum, 16);
        csum += __shfl_xor(csum, 32);
        b2r[ct] = b2[c] - 0.6931471805599453f * csum;   // folds ssp's -ln2
    }

    const int nb = gridDim.x;
    const int t0 = (int)(((long long)blockIdx.x * N_TILES) / nb);
    const int t1 = (int)(((long long)(blockIdx.x + 1) * N_TILES) / nb);
    if (t0 >= t1) return;

    int   curI = idx_i[(size_t)t0 * TILE_E];
    float accV = 0.0f;

    // ---- cross-iteration state: f_ij(t), h-offsets(t) ----
    float4 fa, fb;
    unsigned j0o, j1o, j2o, j3o;
    {
        const int e0 = t0 * TILE_E;
        const float* rp = f_ij + (size_t)(e0 + r0 + l15) * NRBF;
        float4 za = {0,0,0,0}, zb = {0,0,0,0};
        if (quad < 2)       { za = *(const float4*)(rp + quad * 8); zb = *(const float4*)(rp + quad * 8 + 4); }
        else if (quad == 2) { za = *(const float4*)(rp + 16); }
        fa = za; fb = zb;
        const int4 jq = *(const int4*)(idx_j + e0 + rr);
        j0o = (unsigned)(jq.x << 7) + c0; j1o = (unsigned)(jq.y << 7) + c0;
        j2o = (unsigned)(jq.z << 7) + c0; j3o = (unsigned)(jq.w << 7) + c0;
    }

    for (int t = t0; t < t1; ++t) {
        const int e0 = t * TILE_E;
        const int ta = (t + 1 < N_TILES) ? t + 1 : N_TILES - 1;

        // ---- issue current tile's h gathers (consumed after layer1+B1) ----
        float hn[2][4];
        hn[0][0] = h[j0o]; hn[0][1] = h[j1o]; hn[0][2] = h[j2o]; hn[0][3] = h[j3o];
        hn[1][0] = h[j0o + 16]; hn[1][1] = h[j1o + 16];
        hn[1][2] = h[j2o + 16]; hn[1][3] = h[j3o + 16];

        // ---- rcut(t), idx_j(t+1), f_ij(t+1) ----
        const float4 rc = *(const float4*)(rcut + e0 + rr);
        unsigned nj0, nj1, nj2, nj3;
        {
            const int4 jq = *(const int4*)(idx_j + ta * TILE_E + rr);
            nj0 = (unsigned)(jq.x << 7) + c0; nj1 = (unsigned)(jq.y << 7) + c0;
            nj2 = (unsigned)(jq.z << 7) + c0; nj3 = (unsigned)(jq.w << 7) + c0;
        }
        float4 na = {0,0,0,0}, nb2 = {0,0,0,0};
        {
            const float* rp = f_ij + (size_t)(ta * TILE_E + r0 + l15) * NRBF;
            if (quad < 2)       { na = *(const float4*)(rp + quad * 8); nb2 = *(const float4*)(rp + quad * 8 + 4); }
            else if (quad == 2) { na = *(const float4*)(rp + 16); }
        }

        // ================= layer 1: softplus(f_ij @ W1 + b1) -> sTH =================
        {
            const float va[8] = {fa.x, fa.y, fa.z, fa.w, fb.x, fb.y, fb.z, fb.w};
            bf16x8 ah, al;
            #pragma unroll
            for (int j = 0; j < 8; ++j) {
                const unsigned short hb = f2bf(va[j]);
                ah[j] = (short)hb;
                al[j] = (short)f2bf(va[j] - bf2f(hb));
            }
            #pragma unroll
            for (int ct = 0; ct < 2; ++ct) {
                f32x4 d = {0.0f, 0.0f, 0.0f, 0.0f};
                d = __builtin_amdgcn_mfma_f32_16x16x32_bf16(ah, w1h[ct], d, 0, 0, 0);
                d = __builtin_amdgcn_mfma_f32_16x16x32_bf16(al, w1h[ct], d, 0, 0, 0);
                const int c = c0 + ct * 16;
                #pragma unroll
                for (int r = 0; r < 4; ++r)
                    sTH[rr + r][c] = f2bf(sp(d[r] + b1r[ct]));
            }
        }
        lds_barrier();   // B1: sTH visible; sXT free (prev reads done pre-B1)

        // idx_i issued here: consumed after B2, hidden under layer 2
        const int4 i0 = *(const int4*)(idx_i + e0 + qtr * 8);
        const int4 i1 = *(const int4*)(idx_i + e0 + qtr * 8 + 4);

        // ================= layer 2: xij -> sXT =================
        {
            bf16x8 ath[4];
            #pragma unroll
            for (int kk = 0; kk < 4; ++kk)
                ath[kk] = *(const bf16x8*)(&sTH[r0 + l15][kk * 32 + quad * 8]);
            #pragma unroll
            for (int ct = 0; ct < 2; ++ct) {
                f32x4 acc = {0.0f, 0.0f, 0.0f, 0.0f};
                #pragma unroll
                for (int kk = 0; kk < 4; ++kk)
                    acc = __builtin_amdgcn_mfma_f32_16x16x32_bf16(ath[kk], w2h[ct][kk], acc, 0, 0, 0);
                const int c = c0 + ct * 16;
                float4 xv;
                xv.x = (acc[0] + b2r[ct]) * rc.x * hn[ct][0];
                xv.y = (acc[1] + b2r[ct]) * rc.y * hn[ct][1];
                xv.z = (acc[2] + b2r[ct]) * rc.z * hn[ct][2];
                xv.w = (acc[3] + b2r[ct]) * rc.w * hn[ct][3];
                *(float4*)&sXT[c][rr] = xv;
            }
        }
        lds_barrier();   // B2: sXT visible; sTH free for next tile

        // ================= segmented reduce (sorted idx_i) =================
        {
            const float4 x0 = *(const float4*)&sXT[col][qtr * 8];
            const float4 x1 = *(const float4*)&sXT[col][qtr * 8 + 4];
            if (i0.x == curI && i1.w == i0.x) {
                // uniform 8-run continuing current segment (sorted => all equal)
                accV += ((x0.x + x0.y) + (x0.z + x0.w)) + ((x1.x + x1.y) + (x1.z + x1.w));
            } else {
                const float v[8] = {x0.x, x0.y, x0.z, x0.w, x1.x, x1.y, x1.z, x1.w};
                const int   ia[8] = {i0.x, i0.y, i0.z, i0.w, i1.x, i1.y, i1.z, i1.w};
                #pragma unroll
                for (int r = 0; r < 8; ++r) {
                    if (ia[r] != curI) {
                        atomicAdd(&y[curI * 128 + col], accV);
                        curI = ia[r]; accV = v[r];
                    } else accV += v[r];
                }
            }
        }

        // ================= rotate =================
        fa = na; fb = nb2;
        j0o = nj0; j1o = nj1; j2o = nj2; j3o = nj3;
    }
    atomicAdd(&y[curI * 128 + col], accV);
}

// ---------------------------------------------------------------------------
extern "C" void kernel_launch(void* const* d_in, const int* in_sizes, int n_in,
                              void* d_out, int out_size, void* d_ws, size_t ws_size,
                              hipStream_t stream) {
    const float* x      = (const float*)d_in[0];
    const float* f_ij   = (const float*)d_in[1];
    const float* rcut   = (const float*)d_in[2];
    const int*   idx_i  = (const int*)d_in[3];
    const int*   idx_j  = (const int*)d_in[4];
    const float* W_in2f = (const float*)d_in[5];
    const float* W_f1   = (const float*)d_in[6];
    const float* b_f1   = (const float*)d_in[7];
    const float* W_f2   = (const float*)d_in[8];
    const float* b_f2   = (const float*)d_in[9];
    const float* W_o1   = (const float*)d_in[10];
    const float* b_o1   = (const float*)d_in[11];
    const float* W_o2   = (const float*)d_in[12];
    const float* b_o2   = (const float*)d_in[13];

    float* out = (float*)d_out;
    float* h   = (float*)d_ws;   // 25.6 MB; reused as z after cfconv

    // rowgemm1 also grid-stride-zeroes `out` (y accumulator) - no memset dispatch
    rowgemm2<false, false><<<512, 512, 0, stream>>>(x, W_in2f, nullptr, h, N_ATOMS, out);
    edge_mfma<<<1024, 512, 0, stream>>>(f_ij, rcut, idx_i, idx_j, h,
                                        W_f1, b_f1, W_f2, b_f2, out);
    rowgemm2<true, true><<<512, 512, 0, stream>>>(out, W_o1, b_o1, h, N_ATOMS, nullptr);
    rowgemm2<false, true><<<512, 512, 0, stream>>>(h, W_o2, b_o2, out, N_ATOMS, nullptr);
}

// Round 4
// 630.198 us; speedup vs baseline: 1.8835x; 1.8835x over previous
//
#include <hip/hip_runtime.h>
#include <math.h>

#define N_ATOMS 50000
#define N_EDGES 1600000
#define NRBF 20
#define TILE_E 64
#define N_TILES (N_EDGES / TILE_E)   // 25000 exact

typedef __attribute__((ext_vector_type(8))) short bf16x8;
typedef __attribute__((ext_vector_type(4))) short s16x4;
typedef __attribute__((ext_vector_type(4))) float f32x4;

__device__ __forceinline__ float sp(float v) {    // softplus (stable), NO -ln2 shift
    const float a = fabsf(v);
    const float e = exp2f(a * -1.4426950408889634f);
    const float l = log2f(1.0f + e);
    return fmaxf(v, 0.0f) + l * 0.6931471805599453f;
}
__device__ __forceinline__ float ssp(float v) {   // shifted softplus
    const float a = fabsf(v);
    const float e = exp2f(a * -1.4426950408889634f);
    const float l = log2f(1.0f + e);
    return fmaxf(v, 0.0f) + fmaf(l, 0.6931471805599453f, -0.6931471805599453f);
}
__device__ __forceinline__ unsigned short f2bf(float f) {   // fp32 -> bf16 bits, RNE
    unsigned int u = __float_as_uint(f);
    u += 0x7fff + ((u >> 16) & 1);
    return (unsigned short)(u >> 16);
}
__device__ __forceinline__ float bf2f(unsigned short b) {
    return __uint_as_float(((unsigned int)b) << 16);
}
// LDS-only barrier: drains lgkmcnt but NOT vmcnt, so register prefetches of
// global data survive across phases (all inter-wave traffic goes through LDS).
__device__ __forceinline__ void lds_barrier() {
    __asm__ __volatile__("s_waitcnt lgkmcnt(0)\ns_barrier" ::: "memory");
}

// ---------------------------------------------------------------------------
// Row-GEMM (R3-verified, unchanged): A tile staged once per block through LDS
// (bf16 hi/lo planes, scalar f2bf). zbuf!=nullptr: grid-stride-zero that
// buffer first (folds the y-memset into dispatch 1).
template<bool SSP_ACT, bool BIAS>
__global__ __launch_bounds__(512) void rowgemm2(
    const float* __restrict__ A, const float* __restrict__ W,
    const float* __restrict__ bias, float* __restrict__ C, int nrows,
    float* __restrict__ zbuf)
{
    __shared__ short sAh[32][136];   // row stride 272B -> bank-balanced b128
    __shared__ short sAl[32][136];

    if (zbuf) {
        const int n4 = N_ATOMS * 128 / 4;
        const float4 z = {0.0f, 0.0f, 0.0f, 0.0f};
        for (int i = blockIdx.x * blockDim.x + threadIdx.x; i < n4;
             i += gridDim.x * blockDim.x)
            ((float4*)zbuf)[i] = z;
    }

    const int tid  = threadIdx.x;
    const int wave = tid >> 6, lane = tid & 63;
    const int l15  = lane & 15, quad = lane >> 4;
    const int rhalf = wave >> 2, cpair = wave & 3;
    const int r0 = rhalf * 16;
    const int ntiles = (nrows + 31) >> 5;
    const int stride = gridDim.x;

    const int sr0 = tid >> 5;            // rows 0..15
    const int sr1 = sr0 + 16;            // rows 16..31
    const int sc0 = (tid & 31) * 4;      // col group

    bf16x8 wh[2][4], wl[2][4];
    float br[2];
    #pragma unroll
    for (int ct = 0; ct < 2; ++ct) {
        const int c = cpair * 32 + ct * 16 + l15;
        br[ct] = BIAS ? bias[c] : 0.0f;
        #pragma unroll
        for (int kk = 0; kk < 4; ++kk) {
            #pragma unroll
            for (int j = 0; j < 8; ++j) {
                const int k = kk * 32 + quad * 8 + j;
                const float v = W[k * 128 + c];
                const unsigned short hb = f2bf(v);
                wh[ct][kk][j] = (short)hb;
                wl[ct][kk][j] = (short)f2bf(v - bf2f(hb));
            }
        }
    }

    int t = blockIdx.x;
    if (t >= ntiles) return;

    float4 v0, v1;
    {
        const int ra = t * 32 + sr0, rb = t * 32 + sr1;
        v0 = *(const float4*)(A + (size_t)((ra < nrows) ? ra : nrows - 1) * 128 + sc0);
        v1 = *(const float4*)(A + (size_t)((rb < nrows) ? rb : nrows - 1) * 128 + sc0);
    }

    while (true) {
        {
            const float fa[4] = {v0.x, v0.y, v0.z, v0.w};
            const float fb[4] = {v1.x, v1.y, v1.z, v1.w};
            s16x4 ha, la, hbv, lb;
            #pragma unroll
            for (int j = 0; j < 4; ++j) {
                const unsigned short h0 = f2bf(fa[j]);
                ha[j] = (short)h0; la[j] = (short)f2bf(fa[j] - bf2f(h0));
                const unsigned short h1 = f2bf(fb[j]);
                hbv[j] = (short)h1; lb[j] = (short)f2bf(fb[j] - bf2f(h1));
            }
            *(s16x4*)(&sAh[sr0][sc0]) = ha;  *(s16x4*)(&sAl[sr0][sc0]) = la;
            *(s16x4*)(&sAh[sr1][sc0]) = hbv; *(s16x4*)(&sAl[sr1][sc0]) = lb;
        }
        __syncthreads();

        const int tn = t + stride;
        const bool more = (tn < ntiles);
        float4 n0, n1;
        if (more) {
            const int ra = tn * 32 + sr0, rb = tn * 32 + sr1;
            n0 = *(const float4*)(A + (size_t)((ra < nrows) ? ra : nrows - 1) * 128 + sc0);
            n1 = *(const float4*)(A + (size_t)((rb < nrows) ? rb : nrows - 1) * 128 + sc0);
        }

        bf16x8 ah[4], al[4];
        #pragma unroll
        for (int kk = 0; kk < 4; ++kk) {
            ah[kk] = *(const bf16x8*)(&sAh[r0 + l15][kk * 32 + quad * 8]);
            al[kk] = *(const bf16x8*)(&sAl[r0 + l15][kk * 32 + quad * 8]);
        }
        #pragma unroll
        for (int ct = 0; ct < 2; ++ct) {
            f32x4 acc = {0.0f, 0.0f, 0.0f, 0.0f};
            #pragma unroll
            for (int kk = 0; kk < 4; ++kk) {
                acc = __builtin_amdgcn_mfma_f32_16x16x32_bf16(ah[kk], wh[ct][kk], acc, 0, 0, 0);
                acc = __builtin_amdgcn_mfma_f32_16x16x32_bf16(al[kk], wh[ct][kk], acc, 0, 0, 0);
                acc = __builtin_amdgcn_mfma_f32_16x16x32_bf16(ah[kk], wl[ct][kk], acc, 0, 0, 0);
            }
            const int c = cpair * 32 + ct * 16 + l15;
            #pragma unroll
            for (int r = 0; r < 4; ++r) {
                const int row = t * 32 + r0 + quad * 4 + r;
                if (row < nrows) {
                    float v = acc[r] + br[ct];
                    if (SSP_ACT) v = ssp(v);
                    C[(size_t)row * 128 + c] = v;
                }
            }
        }
        if (!more) break;
        __syncthreads();
        v0 = n0; v1 = n1; t = tn;
    }
}

// ---------------------------------------------------------------------------
// Fused edge kernel, v4: TILE_E=64 (2x barrier/fixed-cost amortization).
// 8 waves = (rpair 0..1: which 32-row half) x (cquad 0..3: which 32-col grp);
// each wave: 2 row-groups g x 2 col-tiles ct. Register discipline: only
// f_ij(t+1) carried (real HBM stream); idx_j/rcut/idx_i are sequential
// L1-warm streams loaded in-iteration; h gathers issue at tile top and are
// consumed ~layer-2 epilogue. NO forced 8-wave bound (R3 lesson: spill).
__global__ __launch_bounds__(512, 4) void edge_mfma(
    const float* __restrict__ f_ij, const float* __restrict__ rcut,
    const int* __restrict__ idx_i, const int* __restrict__ idx_j,
    const float* __restrict__ h,
    const float* __restrict__ W1, const float* __restrict__ b1,
    const float* __restrict__ W2, const float* __restrict__ b2,
    float* __restrict__ y)
{
    __shared__ unsigned short sTH[64][136];   // t tile, bf16-hi (17.4 KB)
    __shared__ float sXT[128][68];            // xij^T (34.8 KB); 68%32=4 like R3's 36

    const int tid  = threadIdx.x;
    const int wave = tid >> 6, lane = tid & 63;
    const int l15  = lane & 15, quad = lane >> 4;
    const int rpair = wave >> 2, cquad = wave & 3;
    const int R0  = rpair * 32;
    const int c0  = cquad * 32 + l15;
    const int col = tid & 127, qtr = tid >> 7;

    // ---- weight fragments ----
    bf16x8 w1h[2];
    bf16x8 w2h[2][4];
    float b1r[2], b2r[2];
    #pragma unroll
    for (int ct = 0; ct < 2; ++ct) {
        const int c = c0 + ct * 16;
        b1r[ct] = b1[c];
        #pragma unroll
        for (int j = 0; j < 8; ++j) {
            const int k = quad * 8 + j;
            w1h[ct][j] = (short)f2bf((k < NRBF) ? W1[k * 128 + c] : 0.0f);
        }
        float csum = 0.0f;
        #pragma unroll
        for (int kk = 0; kk < 4; ++kk) {
            #pragma unroll
            for (int j = 0; j < 8; ++j) {
                const float wv = W2[(kk * 32 + quad * 8 + j) * 128 + c];
                const unsigned short hb = f2bf(wv);
                w2h[ct][kk][j] = (short)hb;
                csum += bf2f(hb);
            }
        }
        csum += __shfl_xor(csum, 16);
        csum += __shfl_xor(csum, 32);
        b2r[ct] = b2[c] - 0.6931471805599453f * csum;   // folds ssp's -ln2
    }

    const int nb = gridDim.x;
    const int t0 = (int)(((long long)blockIdx.x * N_TILES) / nb);
    const int t1 = (int)(((long long)(blockIdx.x + 1) * N_TILES) / nb);
    if (t0 >= t1) return;

    int   curI = idx_i[(size_t)t0 * TILE_E + qtr * 16];
    float accV = 0.0f;

    // ---- carried: f_ij fragments for tile t ----
    float4 faA[2], faB[2];
    {
        const int e0 = t0 * TILE_E;
        #pragma unroll
        for (int g = 0; g < 2; ++g) {
            const float* rp = f_ij + (size_t)(e0 + R0 + g * 16 + l15) * NRBF;
            float4 za = {0,0,0,0}, zb = {0,0,0,0};
            if (quad < 2)       { za = *(const float4*)(rp + quad * 8); zb = *(const float4*)(rp + quad * 8 + 4); }
            else if (quad == 2) { za = *(const float4*)(rp + 16); }
            faA[g] = za; faB[g] = zb;
        }
    }

    for (int t = t0; t < t1; ++t) {
        const int e0 = t * TILE_E;
        const int ta = (t + 1 < N_TILES) ? t + 1 : N_TILES - 1;

        // ---- idx_j (L1-warm stream) -> offsets -> h gathers (longest latency) ----
        float hn[2][2][4];
        #pragma unroll
        for (int g = 0; g < 2; ++g) {
            const int4 jq = *(const int4*)(idx_j + e0 + R0 + g * 16 + quad * 4);
            const unsigned o0 = (unsigned)(jq.x << 7) + c0;
            const unsigned o1 = (unsigned)(jq.y << 7) + c0;
            const unsigned o2 = (unsigned)(jq.z << 7) + c0;
            const unsigned o3 = (unsigned)(jq.w << 7) + c0;
            hn[g][0][0] = h[o0]; hn[g][0][1] = h[o1]; hn[g][0][2] = h[o2]; hn[g][0][3] = h[o3];
            hn[g][1][0] = h[o0 + 16]; hn[g][1][1] = h[o1 + 16];
            hn[g][1][2] = h[o2 + 16]; hn[g][1][3] = h[o3 + 16];
        }

        // ---- prefetch f_ij(t+1) (HBM stream, full-latency hide) ----
        float4 naA[2], naB[2];
        #pragma unroll
        for (int g = 0; g < 2; ++g) {
            const float* rp = f_ij + (size_t)(ta * TILE_E + R0 + g * 16 + l15) * NRBF;
            float4 za = {0,0,0,0}, zb = {0,0,0,0};
            if (quad < 2)       { za = *(const float4*)(rp + quad * 8); zb = *(const float4*)(rp + quad * 8 + 4); }
            else if (quad == 2) { za = *(const float4*)(rp + 16); }
            naA[g] = za; naB[g] = zb;
        }

        // ================= layer 1: softplus(f_ij @ W1 + b1) -> sTH =================
        #pragma unroll
        for (int g = 0; g < 2; ++g) {
            const float va[8] = {faA[g].x, faA[g].y, faA[g].z, faA[g].w,
                                 faB[g].x, faB[g].y, faB[g].z, faB[g].w};
            bf16x8 ah, al;
            #pragma unroll
            for (int j = 0; j < 8; ++j) {
                const unsigned short hb = f2bf(va[j]);
                ah[j] = (short)hb;
                al[j] = (short)f2bf(va[j] - bf2f(hb));
            }
            #pragma unroll
            for (int ct = 0; ct < 2; ++ct) {
                f32x4 d = {0.0f, 0.0f, 0.0f, 0.0f};
                d = __builtin_amdgcn_mfma_f32_16x16x32_bf16(ah, w1h[ct], d, 0, 0, 0);
                d = __builtin_amdgcn_mfma_f32_16x16x32_bf16(al, w1h[ct], d, 0, 0, 0);
                const int c = c0 + ct * 16;
                const int rw = R0 + g * 16 + quad * 4;
                #pragma unroll
                for (int r = 0; r < 4; ++r)
                    sTH[rw + r][c] = f2bf(sp(d[r] + b1r[ct]));
            }
        }
        lds_barrier();   // B1: sTH visible; sXT free (prev reads done pre-B1)

        // rcut (L1-warm stream), consumed ~400cy later in epilogue
        const float4 rc0 = *(const float4*)(rcut + e0 + R0 + quad * 4);
        const float4 rc1 = *(const float4*)(rcut + e0 + R0 + 16 + quad * 4);

        // ================= layer 2: xij -> sXT =================
        #pragma unroll
        for (int g = 0; g < 2; ++g) {
            bf16x8 ath[4];
            #pragma unroll
            for (int kk = 0; kk < 4; ++kk)
                ath[kk] = *(const bf16x8*)(&sTH[R0 + g * 16 + l15][kk * 32 + quad * 8]);
            const float4 rcg = g ? rc1 : rc0;
            #pragma unroll
            for (int ct = 0; ct < 2; ++ct) {
                f32x4 acc = {0.0f, 0.0f, 0.0f, 0.0f};
                #pragma unroll
                for (int kk = 0; kk < 4; ++kk)
                    acc = __builtin_amdgcn_mfma_f32_16x16x32_bf16(ath[kk], w2h[ct][kk], acc, 0, 0, 0);
                const int c = c0 + ct * 16;
                float4 xv;
                xv.x = (acc[0] + b2r[ct]) * rcg.x * hn[g][ct][0];
                xv.y = (acc[1] + b2r[ct]) * rcg.y * hn[g][ct][1];
                xv.z = (acc[2] + b2r[ct]) * rcg.z * hn[g][ct][2];
                xv.w = (acc[3] + b2r[ct]) * rcg.w * hn[g][ct][3];
                *(float4*)&sXT[c][R0 + g * 16 + quad * 4] = xv;
            }
        }
        lds_barrier();   // B2: sXT visible; sTH free for next tile

        // ================= segmented reduce: 16 rows/thread, two 8-chunks =================
        #pragma unroll
        for (int ch = 0; ch < 2; ++ch) {
            const int rb = e0 + qtr * 16 + ch * 8;
            const int4 i0 = *(const int4*)(idx_i + rb);
            const int4 i1 = *(const int4*)(idx_i + rb + 4);
            const float4 x0 = *(const float4*)&sXT[col][qtr * 16 + ch * 8];
            const float4 x1 = *(const float4*)&sXT[col][qtr * 16 + ch * 8 + 4];
            if (i0.x == curI && i1.w == i0.x) {
                // uniform 8-run continuing current segment (sorted => all equal)
                accV += ((x0.x + x0.y) + (x0.z + x0.w)) + ((x1.x + x1.y) + (x1.z + x1.w));
            } else {
                const float v[8] = {x0.x, x0.y, x0.z, x0.w, x1.x, x1.y, x1.z, x1.w};
                const int   ia[8] = {i0.x, i0.y, i0.z, i0.w, i1.x, i1.y, i1.z, i1.w};
                #pragma unroll
                for (int r = 0; r < 8; ++r) {
                    if (ia[r] != curI) {
                        atomicAdd(&y[curI * 128 + col], accV);
                        curI = ia[r]; accV = v[r];
                    } else accV += v[r];
                }
            }
        }

        // ================= rotate =================
        faA[0] = naA[0]; faA[1] = naA[1];
        faB[0] = naB[0]; faB[1] = naB[1];
    }
    atomicAdd(&y[curI * 128 + col], accV);
}

// ---------------------------------------------------------------------------
extern "C" void kernel_launch(void* const* d_in, const int* in_sizes, int n_in,
                              void* d_out, int out_size, void* d_ws, size_t ws_size,
                              hipStream_t stream) {
    const float* x      = (const float*)d_in[0];
    const float* f_ij   = (const float*)d_in[1];
    const float* rcut   = (const float*)d_in[2];
    const int*   idx_i  = (const int*)d_in[3];
    const int*   idx_j  = (const int*)d_in[4];
    const float* W_in2f = (const float*)d_in[5];
    const float* W_f1   = (const float*)d_in[6];
    const float* b_f1   = (const float*)d_in[7];
    const float* W_f2   = (const float*)d_in[8];
    const float* b_f2   = (const float*)d_in[9];
    const float* W_o1   = (const float*)d_in[10];
    const float* b_o1   = (const float*)d_in[11];
    const float* W_o2   = (const float*)d_in[12];
    const float* b_o2   = (const float*)d_in[13];

    float* out = (float*)d_out;
    float* h   = (float*)d_ws;   // 25.6 MB; reused as z after cfconv

    // rowgemm1 also grid-stride-zeroes `out` (y accumulator) - no memset dispatch
    rowgemm2<false, false><<<512, 512, 0, stream>>>(x, W_in2f, nullptr, h, N_ATOMS, out);
    edge_mfma<<<512, 512, 0, stream>>>(f_ij, rcut, idx_i, idx_j, h,
                                       W_f1, b_f1, W_f2, b_f2, out);
    rowgemm2<true, true><<<512, 512, 0, stream>>>(out, W_o1, b_o1, h, N_ATOMS, nullptr);
    rowgemm2<false, true><<<512, 512, 0, stream>>>(h, W_o2, b_o2, out, N_ATOMS, nullptr);
}